// Round 1
// baseline (133.288 us; speedup 1.0000x reference)
//
#include <hip/hip_runtime.h>
#include <hip/hip_bf16.h>

#define BB 2
#define NN 1024
#define MM 1024
#define DD 256
#define HH 128

__device__ __forceinline__ float tanh_fast(float x) {
    // tanh(x) = 1 - 2/(exp(2x)+1); exp(2x) = exp2(x * 2*log2(e))
    float e = __builtin_amdgcn_exp2f(x * 2.8853900817779268f);
    return 1.0f - 2.0f * __builtin_amdgcn_rcpf(e + 1.0f);
}

// ---------------- Kernel 1: projections a = q@Wa+ba, b = k@Wb+bb ------------
__global__ __launch_bounds__(128) void proj_kernel(
    const float* __restrict__ query, const float* __restrict__ key,
    const float* __restrict__ Wa_w, const float* __restrict__ Wa_b,
    const float* __restrict__ Wb_w, const float* __restrict__ Wb_b,
    float* __restrict__ A, float* __restrict__ Bm) {
    __shared__ float rows[8][DD];
    const int tid = threadIdx.x;
    const int rb = blockIdx.x * 8;
    const bool isA = rb < BB * NN;
    const float* in = isA ? query : key;
    const float* W  = isA ? Wa_w : Wb_w;
    const float* bias = isA ? Wa_b : Wb_b;
    float* outp = isA ? A : Bm;
    const int base = isA ? rb : rb - BB * NN;

    for (int i = tid; i < 8 * DD; i += 128)
        rows[i >> 8][i & (DD - 1)] = in[(size_t)base * DD + i];
    __syncthreads();

    const int h = tid;  // 0..127
    float acc[8];
    const float bv = bias[h];
#pragma unroll
    for (int r = 0; r < 8; ++r) acc[r] = bv;
    for (int d = 0; d < DD; ++d) {
        const float w = W[d * HH + h];  // coalesced across threads
#pragma unroll
        for (int r = 0; r < 8; ++r) acc[r] = fmaf(rows[r][d], w, acc[r]);
    }
#pragma unroll
    for (int r = 0; r < 8; ++r) outp[(size_t)(base + r) * HH + h] = acc[r];
}

// ---------------- Kernel 2: scores[b,n,m] = sum_h v[h]*tanh(a[n,h]+b[m,h]) --
__global__ __launch_bounds__(256) void scores_kernel(
    const float* __restrict__ A, const float* __restrict__ Bm,
    const float* __restrict__ v_w, float* __restrict__ S) {
    __shared__ float a_t[32][HH + 1];
    __shared__ float b_t[64][HH + 1];
    __shared__ float vv[HH];
    const int tid = threadIdx.x;
    const int m0 = blockIdx.x * 64, n0 = blockIdx.y * 32, b = blockIdx.z;

    for (int i = tid; i < 32 * HH; i += 256)
        a_t[i >> 7][i & (HH - 1)] =
            A[((size_t)(b * NN + n0) + (i >> 7)) * HH + (i & (HH - 1))];
    for (int i = tid; i < 64 * HH; i += 256)
        b_t[i >> 7][i & (HH - 1)] =
            Bm[((size_t)(b * MM + m0) + (i >> 7)) * HH + (i & (HH - 1))];
    if (tid < HH) vv[tid] = v_w[tid];
    __syncthreads();

    const int ml = tid & 63;       // m within tile (lane)
    const int ng = tid >> 6;       // n-group (wave-uniform)
    float acc[8] = {0.f, 0.f, 0.f, 0.f, 0.f, 0.f, 0.f, 0.f};

    for (int h = 0; h < HH; ++h) {
        const float bv = b_t[ml][h];   // conflict-free (pad 129)
        const float vh = vv[h];        // broadcast
#pragma unroll
        for (int i = 0; i < 8; ++i) {
            const float x = a_t[ng * 8 + i][h] + bv;  // broadcast read
            acc[i] = fmaf(vh, tanh_fast(x), acc[i]);
        }
    }

    const size_t rowbase = (size_t)b * NN * MM + (size_t)n0 * MM + m0 + ml;
#pragma unroll
    for (int i = 0; i < 8; ++i)
        S[rowbase + (size_t)(ng * 8 + i) * MM] = acc[i];  // coalesced
}

// ---------------- Kernel 3: softmax over m, then out = attn @ key ------------
__global__ __launch_bounds__(256) void attend_kernel(
    const float* __restrict__ S, const float* __restrict__ key,
    float* __restrict__ out) {
    __shared__ float p[8][MM];
    const int tid = threadIdx.x;
    const int n0 = blockIdx.x * 8, b = blockIdx.y;
    const int wave = tid >> 6, lane = tid & 63;

    // softmax: each wave handles 2 rows
    for (int j = 0; j < 2; ++j) {
        const int r = wave * 2 + j;
        const float* srow = S + (size_t)b * NN * MM + (size_t)(n0 + r) * MM;
        float s[16];
#pragma unroll
        for (int k = 0; k < 16; ++k) s[k] = srow[lane + 64 * k];
        float mx = s[0];
#pragma unroll
        for (int k = 1; k < 16; ++k) mx = fmaxf(mx, s[k]);
#pragma unroll
        for (int o = 32; o > 0; o >>= 1) mx = fmaxf(mx, __shfl_xor(mx, o));
        float sum = 0.f;
#pragma unroll
        for (int k = 0; k < 16; ++k) {
            const float e = __expf(s[k] - mx);
            s[k] = e;
            sum += e;
        }
#pragma unroll
        for (int o = 32; o > 0; o >>= 1) sum += __shfl_xor(sum, o);
        const float inv = 1.0f / sum;
#pragma unroll
        for (int k = 0; k < 16; ++k) p[r][lane + 64 * k] = s[k] * inv;
    }
    __syncthreads();

    // PV: thread d accumulates 8 output rows
    const int d = tid;  // 0..255
    const float* kb = key + (size_t)b * MM * DD;
    float acc[8] = {0.f, 0.f, 0.f, 0.f, 0.f, 0.f, 0.f, 0.f};
    for (int m = 0; m < MM; m += 4) {
        const float kv0 = kb[(size_t)(m + 0) * DD + d];
        const float kv1 = kb[(size_t)(m + 1) * DD + d];
        const float kv2 = kb[(size_t)(m + 2) * DD + d];
        const float kv3 = kb[(size_t)(m + 3) * DD + d];
#pragma unroll
        for (int r = 0; r < 8; ++r) {
            const float4 pv = *reinterpret_cast<const float4*>(&p[r][m]);
            acc[r] = fmaf(pv.x, kv0,
                     fmaf(pv.y, kv1, fmaf(pv.z, kv2, fmaf(pv.w, kv3, acc[r]))));
        }
    }
#pragma unroll
    for (int r = 0; r < 8; ++r)
        out[((size_t)b * NN + n0 + r) * DD + d] = acc[r];
}

extern "C" void kernel_launch(void* const* d_in, const int* in_sizes, int n_in,
                              void* d_out, int out_size, void* d_ws, size_t ws_size,
                              hipStream_t stream) {
    const float* query = (const float*)d_in[0];
    const float* key   = (const float*)d_in[1];
    const float* Wa_w  = (const float*)d_in[2];
    const float* Wa_b  = (const float*)d_in[3];
    const float* Wb_w  = (const float*)d_in[4];
    const float* Wb_b  = (const float*)d_in[5];
    const float* v_w   = (const float*)d_in[6];
    float* out = (float*)d_out;

    float* ws = (float*)d_ws;
    float* A  = ws;                       // B*N*H = 262144 floats
    float* Bm = A + BB * NN * HH;         // B*M*H = 262144 floats
    float* S  = Bm + BB * MM * HH;        // B*N*M = 2097152 floats (10MB total)

    proj_kernel<<<dim3((BB * NN + BB * MM) / 8), dim3(128), 0, stream>>>(
        query, key, Wa_w, Wa_b, Wb_w, Wb_b, A, Bm);
    scores_kernel<<<dim3(MM / 64, NN / 32, BB), dim3(256), 0, stream>>>(
        A, Bm, v_w, S);
    attend_kernel<<<dim3(NN / 8, BB), dim3(256), 0, stream>>>(S, key, out);
}

// Round 2
// 124.098 us; speedup vs baseline: 1.0741x; 1.0741x over previous
//
#include <hip/hip_runtime.h>
#include <hip/hip_bf16.h>

#define BB 2
#define NN 1024
#define MM 1024
#define DD 256
#define HH 128
#define C2LE 2.8853900817779268f   // 2*log2(e)
#define LOG2E 1.4426950408889634f

// ---------------- Kernel 1: projections a = q@Wa+ba, b = k@Wb+bb ------------
__global__ __launch_bounds__(128) void proj_kernel(
    const float* __restrict__ query, const float* __restrict__ key,
    const float* __restrict__ Wa_w, const float* __restrict__ Wa_b,
    const float* __restrict__ Wb_w, const float* __restrict__ Wb_b,
    float* __restrict__ A, float* __restrict__ Bm) {
    __shared__ float rows[8][DD];
    const int tid = threadIdx.x;
    const int rb = blockIdx.x * 8;
    const bool isA = rb < BB * NN;
    const float* in = isA ? query : key;
    const float* W  = isA ? Wa_w : Wb_w;
    const float* bias = isA ? Wa_b : Wb_b;
    float* outp = isA ? A : Bm;
    const int base = isA ? rb : rb - BB * NN;

    for (int i = tid; i < 8 * DD; i += 128)
        rows[i >> 8][i & (DD - 1)] = in[(size_t)base * DD + i];
    __syncthreads();

    const int h = tid;  // 0..127
    float acc[8];
    const float bv = bias[h];
#pragma unroll
    for (int r = 0; r < 8; ++r) acc[r] = bv;
    for (int d = 0; d < DD; ++d) {
        const float w = W[d * HH + h];  // coalesced across threads
#pragma unroll
        for (int r = 0; r < 8; ++r) acc[r] = fmaf(rows[r][d], w, acc[r]);
    }
#pragma unroll
    for (int r = 0; r < 8; ++r) outp[(size_t)(base + r) * HH + h] = acc[r];
}

// ---- Kernel 2: S[b,n,m] = sum_v + sum_h (-2 v_h) * rcp(exp2(a'+b') + 1) ----
// where a' = 2*log2(e)*a, b' = 2*log2(e)*b  (tanh(x) = 1 - 2/(exp(2x)+1))
__global__ __launch_bounds__(256) void scores_kernel(
    const float* __restrict__ A, const float* __restrict__ Bm,
    const float* __restrict__ v_w, float* __restrict__ S) {
    __shared__ float a_t[32][HH];   // pre-scaled a' (broadcast reads)
    __shared__ float b_s[64 * HH];  // pre-scaled b', XOR-swizzled per row
    __shared__ float w_s[HH];       // -2*v
    const int tid = threadIdx.x;
    const int m0 = blockIdx.x * 64, n0 = blockIdx.y * 32, b = blockIdx.z;

    for (int i = tid; i < 32 * HH / 4; i += 256) {
        const int r = i >> 5, h4 = i & 31;
        float4 v = *(const float4*)&A[((size_t)(b * NN + n0 + r)) * HH + h4 * 4];
        v.x *= C2LE; v.y *= C2LE; v.z *= C2LE; v.w *= C2LE;
        *(float4*)&a_t[r][h4 * 4] = v;
    }
    for (int i = tid; i < 64 * HH / 4; i += 256) {
        const int r = i >> 5, h4 = i & 31;
        float4 v = *(const float4*)&Bm[((size_t)(b * MM + m0 + r)) * HH + h4 * 4];
        v.x *= C2LE; v.y *= C2LE; v.z *= C2LE; v.w *= C2LE;
        *(float4*)&b_s[r * HH + ((h4 ^ (r & 7)) << 2)] = v;  // XOR swizzle
    }
    if (tid < HH) w_s[tid] = -2.0f * v_w[tid];
    __syncthreads();

    float sum_v = 0.f;
    for (int h4 = 0; h4 < 32; ++h4) {
        const float4 w4 = *(const float4*)&w_s[h4 * 4];
        sum_v += (w4.x + w4.y) + (w4.z + w4.w);
    }
    sum_v *= -0.5f;  // sum of v_h

    const int ml = tid & 63, ng = tid >> 6;
    const int mlx = ml & 7;
    const float* brow = &b_s[ml * HH];
    float acc[8] = {};
    for (int h4 = 0; h4 < 32; ++h4) {
        const float4 w4 = *(const float4*)&w_s[h4 * 4];                 // broadcast
        const float4 b4 = *(const float4*)&brow[(h4 ^ mlx) << 2];       // swizzled
#pragma unroll
        for (int i = 0; i < 8; ++i) {
            const float4 a4 = *(const float4*)&a_t[ng * 8 + i][h4 * 4]; // broadcast
            const float e0 = __builtin_amdgcn_exp2f(a4.x + b4.x);
            const float e1 = __builtin_amdgcn_exp2f(a4.y + b4.y);
            const float e2 = __builtin_amdgcn_exp2f(a4.z + b4.z);
            const float e3 = __builtin_amdgcn_exp2f(a4.w + b4.w);
            acc[i] = fmaf(w4.x, __builtin_amdgcn_rcpf(e0 + 1.0f), acc[i]);
            acc[i] = fmaf(w4.y, __builtin_amdgcn_rcpf(e1 + 1.0f), acc[i]);
            acc[i] = fmaf(w4.z, __builtin_amdgcn_rcpf(e2 + 1.0f), acc[i]);
            acc[i] = fmaf(w4.w, __builtin_amdgcn_rcpf(e3 + 1.0f), acc[i]);
        }
    }

    const size_t rowbase = (size_t)b * NN * MM + (size_t)n0 * MM + m0 + ml;
#pragma unroll
    for (int i = 0; i < 8; ++i)
        S[rowbase + (size_t)(ng * 8 + i) * MM] = sum_v + acc[i];  // coalesced
}

// ---------------- Kernel 3: softmax over m, then out = attn @ key ------------
__global__ __launch_bounds__(512) void attend_kernel(
    const float* __restrict__ S, const float* __restrict__ key,
    float* __restrict__ out) {
    __shared__ float p[8][MM];
    const int tid = threadIdx.x;
    const int n0 = blockIdx.x * 8, b = blockIdx.y;
    const int wave = tid >> 6, lane = tid & 63;

    // softmax: one wave per row, float4 over m
    {
        const int r = wave;
        const float4* srow4 =
            (const float4*)(S + ((size_t)b * NN + n0 + r) * MM);
        float4 s4[4];
#pragma unroll
        for (int k = 0; k < 4; ++k) s4[k] = srow4[lane + 64 * k];
        float mx = s4[0].x;
#pragma unroll
        for (int k = 0; k < 4; ++k) {
            mx = fmaxf(mx, fmaxf(fmaxf(s4[k].x, s4[k].y), fmaxf(s4[k].z, s4[k].w)));
        }
#pragma unroll
        for (int o = 32; o > 0; o >>= 1) mx = fmaxf(mx, __shfl_xor(mx, o));
        float sum = 0.f;
#pragma unroll
        for (int k = 0; k < 4; ++k) {
            s4[k].x = __builtin_amdgcn_exp2f((s4[k].x - mx) * LOG2E);
            s4[k].y = __builtin_amdgcn_exp2f((s4[k].y - mx) * LOG2E);
            s4[k].z = __builtin_amdgcn_exp2f((s4[k].z - mx) * LOG2E);
            s4[k].w = __builtin_amdgcn_exp2f((s4[k].w - mx) * LOG2E);
            sum += (s4[k].x + s4[k].y) + (s4[k].z + s4[k].w);
        }
#pragma unroll
        for (int o = 32; o > 0; o >>= 1) sum += __shfl_xor(sum, o);
        const float inv = 1.0f / sum;
        float4* prow = (float4*)&p[r][0];
#pragma unroll
        for (int k = 0; k < 4; ++k) {
            float4 v = s4[k];
            v.x *= inv; v.y *= inv; v.z *= inv; v.w *= inv;
            prow[lane + 64 * k] = v;
        }
    }
    __syncthreads();

    // PV: thread (d, rh) accumulates 4 output rows at column d
    const int d = tid & 255;
    const int rh = tid >> 8;  // 0..1 -> rows rh*4 .. rh*4+3
    const float* kb = key + (size_t)b * MM * DD + d;
    float acc0 = 0.f, acc1 = 0.f, acc2 = 0.f, acc3 = 0.f;
#pragma unroll 2
    for (int m = 0; m < MM; m += 4) {
        const float k0 = kb[(size_t)(m + 0) * DD];
        const float k1 = kb[(size_t)(m + 1) * DD];
        const float k2 = kb[(size_t)(m + 2) * DD];
        const float k3 = kb[(size_t)(m + 3) * DD];
        const float4 p0 = *(const float4*)&p[rh * 4 + 0][m];
        const float4 p1 = *(const float4*)&p[rh * 4 + 1][m];
        const float4 p2 = *(const float4*)&p[rh * 4 + 2][m];
        const float4 p3 = *(const float4*)&p[rh * 4 + 3][m];
        acc0 = fmaf(p0.x, k0, fmaf(p0.y, k1, fmaf(p0.z, k2, fmaf(p0.w, k3, acc0))));
        acc1 = fmaf(p1.x, k0, fmaf(p1.y, k1, fmaf(p1.z, k2, fmaf(p1.w, k3, acc1))));
        acc2 = fmaf(p2.x, k0, fmaf(p2.y, k1, fmaf(p2.z, k2, fmaf(p2.w, k3, acc2))));
        acc3 = fmaf(p3.x, k0, fmaf(p3.y, k1, fmaf(p3.z, k2, fmaf(p3.w, k3, acc3))));
    }
    const size_t ob = ((size_t)b * NN + n0 + rh * 4) * DD + d;
    out[ob + 0 * DD] = acc0;
    out[ob + 1 * DD] = acc1;
    out[ob + 2 * DD] = acc2;
    out[ob + 3 * DD] = acc3;
}

extern "C" void kernel_launch(void* const* d_in, const int* in_sizes, int n_in,
                              void* d_out, int out_size, void* d_ws, size_t ws_size,
                              hipStream_t stream) {
    const float* query = (const float*)d_in[0];
    const float* key   = (const float*)d_in[1];
    const float* Wa_w  = (const float*)d_in[2];
    const float* Wa_b  = (const float*)d_in[3];
    const float* Wb_w  = (const float*)d_in[4];
    const float* Wb_b  = (const float*)d_in[5];
    const float* v_w   = (const float*)d_in[6];
    float* out = (float*)d_out;

    float* ws = (float*)d_ws;
    float* A  = ws;                       // B*N*H = 262144 floats
    float* Bm = A + BB * NN * HH;         // B*M*H = 262144 floats
    float* S  = Bm + BB * MM * HH;        // B*N*M = 2097152 floats (10MB total)

    proj_kernel<<<dim3((BB * NN + BB * MM) / 8), dim3(128), 0, stream>>>(
        query, key, Wa_w, Wa_b, Wb_w, Wb_b, A, Bm);
    scores_kernel<<<dim3(MM / 64, NN / 32, BB), dim3(256), 0, stream>>>(
        A, Bm, v_w, S);
    attend_kernel<<<dim3(NN / 8, BB), dim3(512), 0, stream>>>(S, key, out);
}

// Round 3
// 79.442 us; speedup vs baseline: 1.6778x; 1.5621x over previous
//
#include <hip/hip_runtime.h>
#include <hip/hip_bf16.h>

#define BB 2
#define NN 1024
#define MM 1024
#define DD 256
#define HH 128
#define C2LE 2.8853900817779268f   // 2*log2(e)
#define LOG2E 1.4426950408889634f

// ---- Kernel 1: Ea = exp2(C*(q@Wa+ba)), Eb = exp2(C*(k@Wb+bb)), C=2*log2(e)
__global__ __launch_bounds__(256) void proj_kernel(
    const float* __restrict__ query, const float* __restrict__ key,
    const float* __restrict__ Wa_w, const float* __restrict__ Wa_b,
    const float* __restrict__ Wb_w, const float* __restrict__ Wb_b,
    float* __restrict__ Ea, float* __restrict__ Eb) {
    __shared__ float rows[8][DD];     // 8KB
    __shared__ float partial[8][HH];  // 4KB
    const int tid = threadIdx.x;
    const int rb = blockIdx.x * 8;
    const bool isA = rb < BB * NN;
    const float* in = isA ? query : key;
    const float* W  = isA ? Wa_w : Wb_w;
    const float* bias = isA ? Wa_b : Wb_b;
    float* outp = isA ? Ea : Eb;
    const int base = isA ? rb : rb - BB * NN;

    const float4* in4 = (const float4*)(in + (size_t)base * DD);
    float4* rows4 = (float4*)rows;
    rows4[tid] = in4[tid];
    rows4[tid + 256] = in4[tid + 256];
    __syncthreads();

    const int h = tid & 127, half = tid >> 7;
    const int d0 = half * 128;
    float acc[8] = {};
    for (int d = d0; d < d0 + 128; d += 4) {
        const float w0 = W[(d + 0) * HH + h];
        const float w1 = W[(d + 1) * HH + h];
        const float w2 = W[(d + 2) * HH + h];
        const float w3 = W[(d + 3) * HH + h];
#pragma unroll
        for (int r = 0; r < 8; ++r) {
            const float4 rv = *(const float4*)&rows[r][d];
            acc[r] = fmaf(rv.x, w0, fmaf(rv.y, w1, fmaf(rv.z, w2, fmaf(rv.w, w3, acc[r]))));
        }
    }
    if (half) {
#pragma unroll
        for (int r = 0; r < 8; ++r) partial[r][h] = acc[r];
    }
    __syncthreads();
    if (!half) {
        const float bv = bias[h];
#pragma unroll
        for (int r = 0; r < 8; ++r)
            outp[(size_t)(base + r) * HH + h] =
                __builtin_amdgcn_exp2f(C2LE * (acc[r] + partial[r][h] + bv));
    }
}

// ---- Kernel 2: P[b,n,m] = exp( sum_h (-2 v_h) * rcp(Ea*Eb + 1) )  (unnorm,
//      shift-invariant: the +sum(v) constant is dropped)
__global__ __launch_bounds__(256) void scores_kernel(
    const float* __restrict__ Ea, const float* __restrict__ Eb,
    const float* __restrict__ v_w, float* __restrict__ P) {
    __shared__ float a_t[32][HH];   // 16KB broadcast reads
    __shared__ float b_s[64 * HH];  // 32KB, XOR-swizzled rows
    __shared__ float w_s[HH];       // -2*v
    const int tid = threadIdx.x;
    const int m0 = blockIdx.x * 64, n0 = blockIdx.y * 32, b = blockIdx.z;

    for (int i = tid; i < 32 * 32; i += 256) {
        const int r = i >> 5, h4 = i & 31;
        *(float4*)&a_t[r][h4 * 4] =
            *(const float4*)&Ea[((size_t)(b * NN + n0 + r)) * HH + h4 * 4];
    }
    for (int i = tid; i < 64 * 32; i += 256) {
        const int r = i >> 5, h4 = i & 31;
        *(float4*)&b_s[r * HH + ((h4 ^ (r & 7)) << 2)] =
            *(const float4*)&Eb[((size_t)(b * MM + m0 + r)) * HH + h4 * 4];
    }
    if (tid < HH) w_s[tid] = -2.0f * v_w[tid];
    __syncthreads();

    const int ml = tid & 63, ng = tid >> 6;
    const int mlx = ml & 7;
    const float* brow = &b_s[ml * HH];
    float acc[8] = {};
    for (int h4 = 0; h4 < 32; ++h4) {
        const float4 w4 = *(const float4*)&w_s[h4 * 4];            // broadcast
        const float4 b4 = *(const float4*)&brow[(h4 ^ mlx) << 2];  // swizzled
#pragma unroll
        for (int i = 0; i < 8; ++i) {
            const float4 a4 = *(const float4*)&a_t[ng * 8 + i][h4 * 4];  // broadcast
            acc[i] = fmaf(w4.x, __builtin_amdgcn_rcpf(fmaf(a4.x, b4.x, 1.0f)), acc[i]);
            acc[i] = fmaf(w4.y, __builtin_amdgcn_rcpf(fmaf(a4.y, b4.y, 1.0f)), acc[i]);
            acc[i] = fmaf(w4.z, __builtin_amdgcn_rcpf(fmaf(a4.z, b4.z, 1.0f)), acc[i]);
            acc[i] = fmaf(w4.w, __builtin_amdgcn_rcpf(fmaf(a4.w, b4.w, 1.0f)), acc[i]);
        }
    }

    const size_t rowbase = (size_t)b * NN * MM + (size_t)n0 * MM + m0 + ml;
#pragma unroll
    for (int i = 0; i < 8; ++i)
        P[rowbase + (size_t)(ng * 8 + i) * MM] =
            __builtin_amdgcn_exp2f(acc[i] * LOG2E);  // coalesced
}

// ---- Kernel 3: out[n,d] = (sum_m P[n,m]*K[m,d]) / (sum_m P[n,m]) ----------
// 8 waves: waves (r, mh) stage/sum P; PV split over m-halves, LDS-combined.
__global__ __launch_bounds__(512) void attend_kernel(
    const float* __restrict__ P, const float* __restrict__ key,
    float* __restrict__ out) {
    __shared__ float p[4][MM];    // 16KB unnormalized probs
    __shared__ float red[4][DD];  // 4KB partial PV (mh=1)
    __shared__ float sums[4][2];
    const int tid = threadIdx.x;
    const int n0 = blockIdx.x * 4, b = blockIdx.y;
    const int wave = tid >> 6, lane = tid & 63;

    // phase 1: wave (r = wave&3, mh = wave>>2) loads its 512-m half, sums it
    {
        const int r = wave & 3, mh = wave >> 2;
        const float4* prow4 =
            (const float4*)(P + ((size_t)b * NN + n0 + r) * MM + mh * 512);
        const float4 s0 = prow4[lane];
        const float4 s1 = prow4[lane + 64];
        float sum = (s0.x + s0.y) + (s0.z + s0.w) + (s1.x + s1.y) + (s1.z + s1.w);
#pragma unroll
        for (int o = 32; o > 0; o >>= 1) sum += __shfl_xor(sum, o);
        *(float4*)&p[r][mh * 512 + lane * 4] = s0;
        *(float4*)&p[r][mh * 512 + 256 + lane * 4] = s1;
        if (lane == 0) sums[r][mh] = sum;
    }
    __syncthreads();

    // phase 2: thread (d = tid&255, mh = tid>>8) PVs its m-half, 4 rows
    const int d = tid & 255, mh2 = tid >> 8;
    const float* kb = key + (size_t)b * MM * DD + (size_t)mh2 * 512 * DD + d;
    const float* pbase0 = &p[0][mh2 * 512];
    const float* pbase1 = &p[1][mh2 * 512];
    const float* pbase2 = &p[2][mh2 * 512];
    const float* pbase3 = &p[3][mh2 * 512];
    float acc0 = 0.f, acc1 = 0.f, acc2 = 0.f, acc3 = 0.f;
#pragma unroll 4
    for (int m = 0; m < 512; m += 4) {
        const float k0 = kb[(size_t)(m + 0) * DD];
        const float k1 = kb[(size_t)(m + 1) * DD];
        const float k2 = kb[(size_t)(m + 2) * DD];
        const float k3 = kb[(size_t)(m + 3) * DD];
        const float4 p0 = *(const float4*)&pbase0[m];
        const float4 p1 = *(const float4*)&pbase1[m];
        const float4 p2 = *(const float4*)&pbase2[m];
        const float4 p3 = *(const float4*)&pbase3[m];
        acc0 = fmaf(p0.x, k0, fmaf(p0.y, k1, fmaf(p0.z, k2, fmaf(p0.w, k3, acc0))));
        acc1 = fmaf(p1.x, k0, fmaf(p1.y, k1, fmaf(p1.z, k2, fmaf(p1.w, k3, acc1))));
        acc2 = fmaf(p2.x, k0, fmaf(p2.y, k1, fmaf(p2.z, k2, fmaf(p2.w, k3, acc2))));
        acc3 = fmaf(p3.x, k0, fmaf(p3.y, k1, fmaf(p3.z, k2, fmaf(p3.w, k3, acc3))));
    }
    if (mh2) {
        red[0][d] = acc0; red[1][d] = acc1; red[2][d] = acc2; red[3][d] = acc3;
    }
    __syncthreads();
    if (!mh2) {
        const size_t ob = ((size_t)b * NN + n0) * DD + d;
        out[ob + 0 * DD] = (acc0 + red[0][d]) * (1.0f / (sums[0][0] + sums[0][1]));
        out[ob + 1 * DD] = (acc1 + red[1][d]) * (1.0f / (sums[1][0] + sums[1][1]));
        out[ob + 2 * DD] = (acc2 + red[2][d]) * (1.0f / (sums[2][0] + sums[2][1]));
        out[ob + 3 * DD] = (acc3 + red[3][d]) * (1.0f / (sums[3][0] + sums[3][1]));
    }
}

extern "C" void kernel_launch(void* const* d_in, const int* in_sizes, int n_in,
                              void* d_out, int out_size, void* d_ws, size_t ws_size,
                              hipStream_t stream) {
    const float* query = (const float*)d_in[0];
    const float* key   = (const float*)d_in[1];
    const float* Wa_w  = (const float*)d_in[2];
    const float* Wa_b  = (const float*)d_in[3];
    const float* Wb_w  = (const float*)d_in[4];
    const float* Wb_b  = (const float*)d_in[5];
    const float* v_w   = (const float*)d_in[6];
    float* out = (float*)d_out;

    float* ws = (float*)d_ws;
    float* Ea = ws;                       // B*N*H floats
    float* Eb = Ea + BB * NN * HH;        // B*M*H floats
    float* P  = Eb + BB * MM * HH;        // B*N*M floats (10MB total)

    proj_kernel<<<dim3((BB * NN + BB * MM) / 8), dim3(256), 0, stream>>>(
        query, key, Wa_w, Wa_b, Wb_w, Wb_b, Ea, Eb);
    scores_kernel<<<dim3(MM / 64, NN / 32, BB), dim3(256), 0, stream>>>(
        Ea, Eb, v_w, P);
    attend_kernel<<<dim3(NN / 4, BB), dim3(512), 0, stream>>>(P, key, out);
}